// Round 16
// baseline (37.910 us; speedup 1.0000x reference)
//
#include <hip/hip_runtime.h>
#include <stdint.h>

typedef __attribute__((ext_vector_type(8))) short short8;
typedef __attribute__((ext_vector_type(8))) _Float16 half8;
typedef __attribute__((ext_vector_type(4))) float f32x4;
typedef __attribute__((ext_vector_type(4))) uint32_t u32x4;

#define SEQ 256
#define NH 8

__device__ __forceinline__ uint32_t cvt_pk_bf16(float lo, float hi) {
  uint32_t r;
  asm("v_cvt_pk_bf16_f32 %0, %1, %2" : "=v"(r) : "v"(lo), "v"(hi));
  return r;
}
__device__ __forceinline__ uint32_t cvt_pk_f16(float lo, float hi) {
  uint32_t r;
  asm("v_cvt_pkrtz_f16_f32 %0, %1, %2" : "=v"(r) : "v"(lo), "v"(hi));
  return r;
}
__device__ __forceinline__ uint32_t pk_add(uint32_t a, uint32_t b) {
  uint32_t r;
  asm("v_pk_add_f16 %0, %1, %2" : "=v"(r) : "v"(a), "v"(b));
  return r;
}
__device__ __forceinline__ uint32_t pk_relu(uint32_t a) {
  uint32_t r;
  asm("v_pk_max_f16 %0, %1, 0" : "=v"(r) : "v"(a));
  return r;
}

__device__ __forceinline__ short8 pack8(f32x4 a, f32x4 b) {
  union { uint32_t u[4]; short8 v; } t;
  t.u[0] = cvt_pk_bf16(a[0], a[1]);
  t.u[1] = cvt_pk_bf16(a[2], a[3]);
  t.u[2] = cvt_pk_bf16(b[0], b[1]);
  t.u[3] = cvt_pk_bf16(b[2], b[3]);
  return t.v;
}

// ---------------------------------------------------------------------------
// Kernel TB (validated r12, unchanged).
// ---------------------------------------------------------------------------
__global__ __launch_bounds__(256) void build_tables_mfma(
    const int* __restrict__ bseq, const int* __restrict__ cseq,
    const float* __restrict__ epos, const float* __restrict__ ebi,
    const float* __restrict__ ebj, const float* __restrict__ eci,
    const float* __restrict__ ecj, const float* __restrict__ w1,
    float* __restrict__ Tpos, float* __restrict__ Ti, float* __restrict__ Tj) {
  int lane = threadIdx.x & 63, w = threadIdx.x >> 6;
  int task = blockIdx.x * 4 + w;            // [0,1280)
  int lcol = lane & 15, kb = lane >> 4, k8 = kb * 8;
  f32x4 zero = {0.f, 0.f, 0.f, 0.f};

  if (task < 256) {
    int h = task >> 5, ft = task & 31;
    short8 bf[2];
#pragma unroll
    for (int kt = 0; kt < 2; ++kt) {
      union { uint32_t u[4]; short8 v; } t;
#pragma unroll
      for (int r = 0; r < 4; ++r) {
        float lo = w1[(k8 + 2 * r) * 256 + (kt * 16 + lcol) * 8 + h];
        float hi = w1[(k8 + 2 * r + 1) * 256 + (kt * 16 + lcol) * 8 + h];
        t.u[r] = cvt_pk_bf16(lo, hi);
      }
      bf[kt] = t.v;
    }
    const float* ep = epos + ((ft * 16 + lcol) * NH + h) * 32 + k8;
    short8 af = pack8(*(const f32x4*)ep, *(const f32x4*)(ep + 4));
#pragma unroll
    for (int kt = 0; kt < 2; ++kt) {
      f32x4 d = __builtin_amdgcn_mfma_f32_16x16x32_bf16(af, bf[kt], zero, 0, 0, 0);
#pragma unroll
      for (int r = 0; r < 4; ++r)
        Tpos[h * 16384 + (ft * 16 + kb * 4 + r) * 32 + kt * 16 + lcol] = d[r];
    }
  } else {
    int isI = task < 768;
    int t2 = task - (isI ? 256 : 768);
    int h = t2 >> 6, bm = t2 & 63;
    int p0 = isI ? ((kb < 2 ? 32 : 48) + k8)
                 : ((kb < 2 ? 48 : 64) + k8);
    short8 bf[2];
#pragma unroll
    for (int kt = 0; kt < 2; ++kt) {
      union { uint32_t u[4]; short8 v; } t;
#pragma unroll
      for (int r = 0; r < 4; ++r) {
        float lo = w1[(p0 + 2 * r) * 256 + (kt * 16 + lcol) * 8 + h];
        float hi = w1[(p0 + 2 * r + 1) * 256 + (kt * 16 + lcol) * 8 + h];
        t.u[r] = cvt_pk_bf16(lo, hi);
      }
      bf[kt] = t.v;
    }
    int gm = bm * 16 + lcol;
    int bi = bseq[gm], ci = cseq[gm];
    const float* eB = isI ? ebi : ebj;
    const float* eC = isI ? eci : ecj;
    const float* src = (kb < 2) ? eB + (bi * NH + h) * 16 + k8
                                : eC + (ci * NH + h) * 16 + (k8 - 16);
    short8 af = pack8(*(const f32x4*)src, *(const f32x4*)(src + 4));
    float* T = isI ? Ti : Tj;
#pragma unroll
    for (int kt = 0; kt < 2; ++kt) {
      f32x4 d = __builtin_amdgcn_mfma_f32_16x16x32_bf16(af, bf[kt], zero, 0, 0, 0);
#pragma unroll
      for (int r = 0; r < 4; ++r)
        T[h * 32768 + (bm * 16 + kb * 4 + r) * 32 + kt * 16 + lcol] = d[r];
    }
  }
}

// ---------------------------------------------------------------------------
// Kernel MAIN (r15 body, UNCHANGED math) -- MEASUREMENT ROUND: grid = 1536,
// wg = blockIdx.x % 512, so each logical block runs 3x writing identical
// values (benign duplicate writes). Makes the dispatch long enough to appear
// in the rocprof top-5 with full counters, and tests TLP supply (32 vs 16
// waves/CU) with identical per-block work.
// ---------------------------------------------------------------------------
__global__ __launch_bounds__(512, 4) void dis_att_main(
    const float* __restrict__ attn, const float* __restrict__ w2,
    const float* __restrict__ w3, const float* __restrict__ Tpos,
    const float* __restrict__ Ti, const float* __restrict__ Tj,
    float* __restrict__ out) {
  __shared__ uint32_t sApB[127][20];
  __shared__ uint32_t sAiB[64][20];
  __shared__ uint32_t sAjB[64][20];
  int tid = threadIdx.x;
  int wg = blockIdx.x % 512;                // 512 = b(4) h(8) mt(4) nt(4)
  int nt = wg & 3, mt = (wg >> 2) & 3, h = (wg >> 4) & 7, b = wg >> 7;
  int m0 = mt * 64, n0 = nt * 64;
  int f0 = m0 - n0 + 193;

  {  // stage + pack to f16
    int r = tid >> 1, q = tid & 1;
    const float* src = nullptr;
    uint32_t* dst = nullptr;
    if (r < 127) {
      src = Tpos + h * 16384 + (f0 + r) * 32;
      dst = &sApB[r][0];
    } else if (r < 191) {
      src = Ti + h * 32768 + (b * 256 + m0 + (r - 127)) * 32;
      dst = &sAiB[r - 127][0];
    } else if (r < 255) {
      src = Tj + h * 32768 + (b * 256 + n0 + (r - 191)) * 32;
      dst = &sAjB[r - 191][0];
    }
    if (src) {
      const float* s16 = src + q * 16;
      f32x4 v0 = *(const f32x4*)s16;
      f32x4 v1 = *(const f32x4*)(s16 + 4);
      f32x4 v2 = *(const f32x4*)(s16 + 8);
      f32x4 v3 = *(const f32x4*)(s16 + 12);
      u32x4 o0 = {cvt_pk_f16(v0[0], v0[1]), cvt_pk_f16(v0[2], v0[3]),
                  cvt_pk_f16(v1[0], v1[1]), cvt_pk_f16(v1[2], v1[3])};
      u32x4 o1 = {cvt_pk_f16(v2[0], v2[1]), cvt_pk_f16(v2[2], v2[3]),
                  cvt_pk_f16(v3[0], v3[1]), cvt_pk_f16(v3[2], v3[3])};
      *(u32x4*)(dst + q * 8) = o0;
      *(u32x4*)(dst + q * 8 + 4) = o1;
    }
  }
  __syncthreads();

  int lane = tid & 63, w = tid >> 6;
  int lcol = lane & 15, kb = lane >> 4, k8 = kb * 8, kq = kb * 4;
  f32x4 zero = {0.f, 0.f, 0.f, 0.f};

  union { uint32_t u[4]; half8 v; } w2f;
#pragma unroll
  for (int r = 0; r < 4; ++r) {
    float lo = w2[(k8 + 2 * r) * 128 + lcol * 8 + h];
    float hi = w2[(k8 + 2 * r + 1) * 128 + lcol * 8 + h];
    w2f.u[r] = cvt_pk_f16(lo, hi);
  }
  float w3v[4];
#pragma unroll
  for (int r = 0; r < 4; ++r) w3v[r] = w3[(kb * 4 + r) * 8 + h];

  u32x4 ajP[4];
#pragma unroll
  for (int ng = 0; ng < 4; ++ng)
    ajP[ng] = *(const u32x4*)&sAjB[ng * 16 + lcol][kq];

  const float* attn_b = attn + (b * NH + h) * SEQ * SEQ;
  float* out_b = out + (b * NH + h) * SEQ * SEQ;
  int bit4 = kb & 1, bit5 = kb & 2;

#pragma unroll
  for (int s = 0; s < 2; ++s) {
    int mb = w * 8 + s * 4;
    float av[4];
    int idxs[4];
#pragma unroll
    for (int ng = 0; ng < 4; ++ng) {
      idxs[ng] = (m0 + mb + kb) * SEQ + n0 + ng * 16 + lcol;
      av[ng] = attn_b[idxs[ng]];
    }
    u32x4 aiP[4];
#pragma unroll
    for (int mi = 0; mi < 4; ++mi)
      aiP[mi] = *(const u32x4*)&sAiB[mb + mi][kq];
#pragma unroll
    for (int ng = 0; ng < 4; ++ng) {
      int nl = ng * 16 + lcol;
      u32x4 pP[4];
#pragma unroll
      for (int mi = 0; mi < 4; ++mi)
        pP[mi] = *(const u32x4*)&sApB[mb + mi - nl + 63][kq];
      __builtin_amdgcn_sched_barrier(0);
      float part[4];
#pragma unroll
      for (int mi = 0; mi < 4; ++mi) {
        union { uint32_t u[4]; half8 v; } ef;
#pragma unroll
        for (int r = 0; r < 4; ++r)
          ef.u[r] = pk_relu(pk_add(pk_add(pP[mi][r], aiP[mi][r]), ajP[ng][r]));
        f32x4 d = __builtin_amdgcn_mfma_f32_16x16x32_f16(w2f.v, ef.v, zero, 0, 0, 0);
        part[mi] = fmaxf(d[0], 0.f) * w3v[0] + fmaxf(d[1], 0.f) * w3v[1] +
                   fmaxf(d[2], 0.f) * w3v[2] + fmaxf(d[3], 0.f) * w3v[3];
      }
      float mineA = bit4 ? part[1] : part[0];
      float sendA = bit4 ? part[0] : part[1];
      float mineB = bit4 ? part[3] : part[2];
      float sendB = bit4 ? part[2] : part[3];
      mineA += __shfl_xor(sendA, 16, 64);
      mineB += __shfl_xor(sendB, 16, 64);
      float keep = bit5 ? mineB : mineA;
      float send = bit5 ? mineA : mineB;
      float res = keep + __shfl_xor(send, 32, 64);
      out_b[idxs[ng]] = av[ng] + res;
    }
  }
}

extern "C" void kernel_launch(void* const* d_in, const int* in_sizes, int n_in,
                              void* d_out, int out_size, void* d_ws, size_t ws_size,
                              hipStream_t stream) {
  const float* attn = (const float*)d_in[0];
  const int* bseq   = (const int*)d_in[1];
  const int* cseq   = (const int*)d_in[2];
  const float* epos = (const float*)d_in[3];
  const float* ebi  = (const float*)d_in[4];
  const float* ebj  = (const float*)d_in[5];
  const float* eci  = (const float*)d_in[6];
  const float* ecj  = (const float*)d_in[7];
  const float* w1   = (const float*)d_in[8];
  const float* w2   = (const float*)d_in[9];
  const float* w3   = (const float*)d_in[10];
  float* out = (float*)d_out;

  float* Tpos = (float*)d_ws;              // 8*512*32  = 131072 f32
  float* Ti   = Tpos + 131072;             // 8*1024*32 = 262144 f32
  float* Tj   = Ti + 262144;               // 262144 f32  (total 2.62 MB)

  hipLaunchKernelGGL(build_tables_mfma, dim3(320), dim3(256), 0, stream,
                     bseq, cseq, epos, ebi, ebj, eci, ecj, w1, Tpos, Ti, Tj);
  hipLaunchKernelGGL(dis_att_main, dim3(1536), dim3(512), 0, stream,
                     attn, w2, w3, Tpos, Ti, Tj, out);
}

// Round 17
// 22.424 us; speedup vs baseline: 1.6906x; 1.6906x over previous
//
#include <hip/hip_runtime.h>
#include <stdint.h>

typedef __attribute__((ext_vector_type(8))) short short8;
typedef __attribute__((ext_vector_type(4))) float f32x4;

#define SEQ 256
#define NH 8

__device__ __forceinline__ uint32_t cvt_pk_bf16(float lo, float hi) {
  uint32_t r;
  asm("v_cvt_pk_bf16_f32 %0, %1, %2" : "=v"(r) : "v"(lo), "v"(hi));
  return r;
}

__device__ __forceinline__ short8 pack8(f32x4 a, f32x4 b) {
  union { uint32_t u[4]; short8 v; } t;
  t.u[0] = cvt_pk_bf16(a[0], a[1]);
  t.u[1] = cvt_pk_bf16(a[2], a[3]);
  t.u[2] = cvt_pk_bf16(b[0], b[1]);
  t.u[3] = cvt_pk_bf16(b[2], b[3]);
  return t.v;
}

// ---------------------------------------------------------------------------
// ONE fused kernel. Block = (b, h, 64m x 64n), 512 thr (8 waves), 512 blocks.
// Phase 0: stage w1[:,:,h] (12 KB) -> sW1 LDS, once per block. This converts
//   phase 1's w1 fragment GATHERS (32-line TA cost per load, the r16-measured
//   dominant cost) into cheap ds_reads.
// Phase 1 (r5-validated MFMA conventions): build pre-ReLU layer-1 tables in
//   LDS: sAp[rl][k] (rl=m-n+63, 128 rows, row127 junk), sAi[64], sAj[64].
// Phase 2 (r7/r12-validated): per ng-group batch-load pA/pB, 4 chains of
//   e1=relu(Ap+Ai+Aj)->bf16 -> mfma(A=w2^T) -> relu-dot w3; 3-shuffle
//   butterfly reduce; coalesced attn-add store.
// No workspace, no cross-kernel deps: replay-proof.
// ---------------------------------------------------------------------------
__global__ __launch_bounds__(512, 4) void dis_att_fused(
    const float* __restrict__ attn, const int* __restrict__ bseq,
    const int* __restrict__ cseq, const float* __restrict__ epos,
    const float* __restrict__ ebi, const float* __restrict__ ebj,
    const float* __restrict__ eci, const float* __restrict__ ecj,
    const float* __restrict__ w1, const float* __restrict__ w2,
    const float* __restrict__ w3, float* __restrict__ out) {
  __shared__ float sW1[96][33];    // w1[p][k] slice for this h (12.7 KB)
  __shared__ float sAp[128][36];
  __shared__ float sAi[64][36];
  __shared__ float sAj[64][36];
  int tid = threadIdx.x;
  int wg = blockIdx.x;                     // 512 = b(4) h(8) mt(4) nt(4)
  int nt = wg & 3, mt = (wg >> 2) & 3, h = (wg >> 4) & 7, b = wg >> 7;
  int m0 = mt * 64, n0 = nt * 64;
  int f0 = m0 - n0 + 193;                  // global f of sAp row 0
  int lane = tid & 63, w = tid >> 6;
  int lcol = lane & 15, kb = lane >> 4, k8 = kb * 8;
  f32x4 zero = {0.f, 0.f, 0.f, 0.f};

  // ---------------- phase 0: stage w1 slice ----------------
#pragma unroll
  for (int i = 0; i < 6; ++i) {
    int idx = tid + 512 * i;               // = p*32 + k, 3072 total
    sW1[idx >> 5][idx & 31] = w1[(idx >> 5) * 256 + (idx & 31) * 8 + h];
  }
  __syncthreads();

  // ---------------- phase 1: build tables (r5 structure, sW1 frags) -------
  if (w < 4) {                             // Apos band: m-tiles {w, w+4}
    short8 bf[2];
#pragma unroll
    for (int kt = 0; kt < 2; ++kt) {       // B = W_pos[k=p][kout]
      union { uint32_t u[4]; short8 v; } t;
#pragma unroll
      for (int r = 0; r < 4; ++r)
        t.u[r] = cvt_pk_bf16(sW1[k8 + 2 * r][kt * 16 + lcol],
                             sW1[k8 + 2 * r + 1][kt * 16 + lcol]);
      bf[kt] = t.v;
    }
#pragma unroll
    for (int t = 0; t < 2; ++t) {
      int mt_ = w + t * 4;                 // tile 0..7 (rows mt_*16..+15)
      int frow = f0 + mt_ * 16 + lcol;
      if (frow > 511) frow = 511;          // row 127 junk, never read
      const float* ep = epos + (frow * NH + h) * 32 + k8;
      short8 af = pack8(*(const f32x4*)ep, *(const f32x4*)(ep + 4));
#pragma unroll
      for (int kt = 0; kt < 2; ++kt) {
        f32x4 d = __builtin_amdgcn_mfma_f32_16x16x32_bf16(af, bf[kt], zero, 0, 0, 0);
#pragma unroll
        for (int r = 0; r < 4; ++r)
          sAp[mt_ * 16 + kb * 4 + r][kt * 16 + lcol] = d[r];
      }
    }
  } else {                                 // Ai (waves 4,5) / Aj (waves 6,7)
    int isI = w < 6;
    int p0 = isI ? ((kb < 2 ? 32 : 48) + k8)    // W_i rows: 32..47 | 64..79
                 : ((kb < 2 ? 48 : 64) + k8);   // W_j rows: 48..63 | 80..95
    short8 bf[2];
#pragma unroll
    for (int kt = 0; kt < 2; ++kt) {
      union { uint32_t u[4]; short8 v; } t;
#pragma unroll
      for (int r = 0; r < 4; ++r)
        t.u[r] = cvt_pk_bf16(sW1[p0 + 2 * r][kt * 16 + lcol],
                             sW1[p0 + 2 * r + 1][kt * 16 + lcol]);
      bf[kt] = t.v;
    }
    const float* eB = isI ? ebi : ebj;
    const float* eC = isI ? eci : ecj;
    int base = isI ? m0 : n0;
    int w2_ = isI ? (w - 4) : (w - 6);
#pragma unroll
    for (int t = 0; t < 2; ++t) {
      int mt_ = w2_ * 2 + t;               // tile 0..3 (rows mt_*16..+15)
      int gm = b * SEQ + base + mt_ * 16 + lcol;
      int bi = bseq[gm], ci = cseq[gm];
      const float* src = (kb < 2) ? eB + (bi * NH + h) * 16 + k8
                                  : eC + (ci * NH + h) * 16 + (k8 - 16);
      short8 af = pack8(*(const f32x4*)src, *(const f32x4*)(src + 4));
#pragma unroll
      for (int kt = 0; kt < 2; ++kt) {
        f32x4 d = __builtin_amdgcn_mfma_f32_16x16x32_bf16(af, bf[kt], zero, 0, 0, 0);
#pragma unroll
        for (int r = 0; r < 4; ++r) {
          float* T = isI ? &sAi[mt_ * 16 + kb * 4 + r][kt * 16 + lcol]
                         : &sAj[mt_ * 16 + kb * 4 + r][kt * 16 + lcol];
          *T = d[r];
        }
      }
    }
  }
  __syncthreads();

  // ---------------- phase 2: main compute (validated r7/r12) ----------------
  union { uint32_t u[4]; short8 v; } w2f;  // A = w2^T: row=lcol, k=k8..k8+7
#pragma unroll
  for (int r = 0; r < 4; ++r) {
    float lo = w2[(k8 + 2 * r) * 128 + lcol * 8 + h];
    float hi = w2[(k8 + 2 * r + 1) * 128 + lcol * 8 + h];
    w2f.u[r] = cvt_pk_bf16(lo, hi);
  }
  float w3v[4];
#pragma unroll
  for (int r = 0; r < 4; ++r) w3v[r] = w3[(kb * 4 + r) * 8 + h];

  f32x4 ajA[4], ajB[4];
#pragma unroll
  for (int ng = 0; ng < 4; ++ng) {
    int nl = ng * 16 + lcol;
    ajA[ng] = *(const f32x4*)&sAj[nl][k8];
    ajB[ng] = *(const f32x4*)&sAj[nl][k8 + 4];
  }

  const float* attn_b = attn + (b * NH + h) * SEQ * SEQ;
  float* out_b = out + (b * NH + h) * SEQ * SEQ;
  int bit4 = kb & 1, bit5 = kb & 2;

#pragma unroll
  for (int s = 0; s < 2; ++s) {
    int mb = w * 8 + s * 4;
    float av[4];
    int idxs[4];
#pragma unroll
    for (int ng = 0; ng < 4; ++ng) {
      idxs[ng] = (m0 + mb + kb) * SEQ + n0 + ng * 16 + lcol;
      av[ng] = attn_b[idxs[ng]];
    }
    f32x4 aiA[4], aiB[4];
#pragma unroll
    for (int mi = 0; mi < 4; ++mi) {
      aiA[mi] = *(const f32x4*)&sAi[mb + mi][k8];
      aiB[mi] = *(const f32x4*)&sAi[mb + mi][k8 + 4];
    }
#pragma unroll
    for (int ng = 0; ng < 4; ++ng) {
      int nl = ng * 16 + lcol;
      f32x4 pA[4], pB[4];
#pragma unroll
      for (int mi = 0; mi < 4; ++mi) {
        int rl = mb + mi - nl + 63;
        pA[mi] = *(const f32x4*)&sAp[rl][k8];
        pB[mi] = *(const f32x4*)&sAp[rl][k8 + 4];
      }
      __builtin_amdgcn_sched_barrier(0);
      float part[4];
#pragma unroll
      for (int mi = 0; mi < 4; ++mi) {
        f32x4 s0 = pA[mi] + aiA[mi] + ajA[ng];
        f32x4 s1 = pB[mi] + aiB[mi] + ajB[ng];
        union { uint32_t u[4]; short8 v; } ef;
        ef.u[0] = cvt_pk_bf16(fmaxf(s0[0], 0.f), fmaxf(s0[1], 0.f));
        ef.u[1] = cvt_pk_bf16(fmaxf(s0[2], 0.f), fmaxf(s0[3], 0.f));
        ef.u[2] = cvt_pk_bf16(fmaxf(s1[0], 0.f), fmaxf(s1[1], 0.f));
        ef.u[3] = cvt_pk_bf16(fmaxf(s1[2], 0.f), fmaxf(s1[3], 0.f));
        f32x4 d = __builtin_amdgcn_mfma_f32_16x16x32_bf16(w2f.v, ef.v, zero, 0, 0, 0);
        part[mi] = fmaxf(d[0], 0.f) * w3v[0] + fmaxf(d[1], 0.f) * w3v[1] +
                   fmaxf(d[2], 0.f) * w3v[2] + fmaxf(d[3], 0.f) * w3v[3];
      }
      float mineA = bit4 ? part[1] : part[0];
      float sendA = bit4 ? part[0] : part[1];
      float mineB = bit4 ? part[3] : part[2];
      float sendB = bit4 ? part[2] : part[3];
      mineA += __shfl_xor(sendA, 16, 64);
      mineB += __shfl_xor(sendB, 16, 64);
      float keep = bit5 ? mineB : mineA;
      float send = bit5 ? mineA : mineB;
      float res = keep + __shfl_xor(send, 32, 64);
      out_b[idxs[ng]] = av[ng] + res;
    }
  }
}

extern "C" void kernel_launch(void* const* d_in, const int* in_sizes, int n_in,
                              void* d_out, int out_size, void* d_ws, size_t ws_size,
                              hipStream_t stream) {
  const float* attn = (const float*)d_in[0];
  const int* bseq   = (const int*)d_in[1];
  const int* cseq   = (const int*)d_in[2];
  const float* epos = (const float*)d_in[3];
  const float* ebi  = (const float*)d_in[4];
  const float* ebj  = (const float*)d_in[5];
  const float* eci  = (const float*)d_in[6];
  const float* ecj  = (const float*)d_in[7];
  const float* w1   = (const float*)d_in[8];
  const float* w2   = (const float*)d_in[9];
  const float* w3   = (const float*)d_in[10];
  float* out = (float*)d_out;

  hipLaunchKernelGGL(dis_att_fused, dim3(512), dim3(512), 0, stream,
                     attn, bseq, cseq, epos, ebi, ebj, eci, ecj, w1, w2, w3, out);
}

// Round 18
// 22.251 us; speedup vs baseline: 1.7037x; 1.0078x over previous
//
#include <hip/hip_runtime.h>
#include <stdint.h>

typedef __attribute__((ext_vector_type(8))) short short8;
typedef __attribute__((ext_vector_type(4))) float f32x4;

#define SEQ 256
#define NH 8

__device__ __forceinline__ uint32_t cvt_pk_bf16(float lo, float hi) {
  uint32_t r;
  asm("v_cvt_pk_bf16_f32 %0, %1, %2" : "=v"(r) : "v"(lo), "v"(hi));
  return r;
}

__device__ __forceinline__ short8 pack8(f32x4 a, f32x4 b) {
  union { uint32_t u[4]; short8 v; } t;
  t.u[0] = cvt_pk_bf16(a[0], a[1]);
  t.u[1] = cvt_pk_bf16(a[2], a[3]);
  t.u[2] = cvt_pk_bf16(b[0], b[1]);
  t.u[3] = cvt_pk_bf16(b[2], b[3]);
  return t.v;
}

// ---------------------------------------------------------------------------
// ONE fused kernel. Block = (b, h, 64m x 64n), 512 thr (8 waves), 512 blocks.
// Phase 0 (NEW): stage ALL phase-1 operands with coalesced / once-per-row
//   loads: sW1 <- w1[:,:,h] (12.7 KB); sAp <- RAW epos band (128 rows x 32,
//   f32x4 8 thr/row); sAi/sAj <- RAW emb rows ([ebi|eci] / [ebj|ecj], one
//   64B row-half per 4 threads). Kills the 16-row/inst fragment gathers.
// Phase 1: A-fragments via ds_read from raw LDS; B-fragments from sW1;
//   MFMA into regs (r5-validated conventions); barrier; write D IN-PLACE
//   over sAp/sAi/sAj (read-to-reg -> barrier -> write: race-free).
// Phase 2 (r7/r12-validated, verbatim): batched pA/pB chains + butterfly.
// ---------------------------------------------------------------------------
__global__ __launch_bounds__(512, 4) void dis_att_fused(
    const float* __restrict__ attn, const int* __restrict__ bseq,
    const int* __restrict__ cseq, const float* __restrict__ epos,
    const float* __restrict__ ebi, const float* __restrict__ ebj,
    const float* __restrict__ eci, const float* __restrict__ ecj,
    const float* __restrict__ w1, const float* __restrict__ w2,
    const float* __restrict__ w3, float* __restrict__ out) {
  __shared__ float sW1[96][33];
  __shared__ float sAp[128][36];
  __shared__ float sAi[64][36];
  __shared__ float sAj[64][36];
  int tid = threadIdx.x;
  int wg = blockIdx.x;                     // 512 = b(4) h(8) mt(4) nt(4)
  int nt = wg & 3, mt = (wg >> 2) & 3, h = (wg >> 4) & 7, b = wg >> 7;
  int m0 = mt * 64, n0 = nt * 64;
  int f0 = m0 - n0 + 193;                  // global f of sAp row 0
  int lane = tid & 63, w = tid >> 6;
  int lcol = lane & 15, kb = lane >> 4, k8 = kb * 8;
  f32x4 zero = {0.f, 0.f, 0.f, 0.f};

  // ---------------- phase 0: coalesced staging ----------------
#pragma unroll
  for (int i = 0; i < 6; ++i) {
    int idx = tid + 512 * i;               // p*32 + k, 3072 total
    sW1[idx >> 5][idx & 31] = w1[(idx >> 5) * 256 + (idx & 31) * 8 + h];
  }
  {
    int r = tid >> 3, q = tid & 7;
    // raw epos band (rows clamped at 511; row 127 junk in extreme tiles)
#pragma unroll
    for (int p = 0; p < 2; ++p) {
      int row = r + 64 * p;
      int f = f0 + row; if (f > 511) f = 511;
      *(f32x4*)&sAp[row][q * 4] = *(const f32x4*)(epos + (f * NH + h) * 32 + q * 4);
    }
    // raw emb rows: sAi[r] = [ebi(16) | eci(16)], sAj[r] = [ebj | ecj]
    int gmi = b * SEQ + m0 + r, gmj = b * SEQ + n0 + r;
    if (q < 4) {
      int bi = bseq[gmi], bj = bseq[gmj];
      *(f32x4*)&sAi[r][q * 4] = *(const f32x4*)(ebi + (bi * NH + h) * 16 + q * 4);
      *(f32x4*)&sAj[r][q * 4] = *(const f32x4*)(ebj + (bj * NH + h) * 16 + q * 4);
    } else {
      int ci = cseq[gmi], cj = cseq[gmj];
      *(f32x4*)&sAi[r][q * 4] = *(const f32x4*)(eci + (ci * NH + h) * 16 + (q - 4) * 4);
      *(f32x4*)&sAj[r][q * 4] = *(const f32x4*)(ecj + (cj * NH + h) * 16 + (q - 4) * 4);
    }
  }
  __syncthreads();

  // ---------------- phase 1a: fragment reads (LDS -> regs) ----------------
  short8 af[2], bf[2];
  if (w < 4) {                             // Apos: tiles {w, w+4}
#pragma unroll
    for (int kt = 0; kt < 2; ++kt) {
      union { uint32_t u[4]; short8 v; } t;
#pragma unroll
      for (int r = 0; r < 4; ++r)
        t.u[r] = cvt_pk_bf16(sW1[k8 + 2 * r][kt * 16 + lcol],
                             sW1[k8 + 2 * r + 1][kt * 16 + lcol]);
      bf[kt] = t.v;
    }
#pragma unroll
    for (int t = 0; t < 2; ++t) {
      int row = (w + t * 4) * 16 + lcol;
      af[t] = pack8(*(const f32x4*)&sAp[row][k8],
                    *(const f32x4*)&sAp[row][k8 + 4]);
    }
  } else {                                 // Ai (waves 4,5) / Aj (waves 6,7)
    int isI = w < 6;
    int p0 = isI ? ((kb < 2 ? 32 : 48) + k8)    // W rows: bi 32..47 | ci 64..79
                 : ((kb < 2 ? 48 : 64) + k8);   //         bj 48..63 | cj 80..95
#pragma unroll
    for (int kt = 0; kt < 2; ++kt) {
      union { uint32_t u[4]; short8 v; } t;
#pragma unroll
      for (int r = 0; r < 4; ++r)
        t.u[r] = cvt_pk_bf16(sW1[p0 + 2 * r][kt * 16 + lcol],
                             sW1[p0 + 2 * r + 1][kt * 16 + lcol]);
      bf[kt] = t.v;
    }
    int w2_ = isI ? (w - 4) : (w - 6);
#pragma unroll
    for (int t = 0; t < 2; ++t) {
      int row = (w2_ * 2 + t) * 16 + lcol;
      const float* base = isI ? &sAi[row][0] : &sAj[row][0];
      af[t] = pack8(*(const f32x4*)(base + k8), *(const f32x4*)(base + k8 + 4));
    }
  }
  __syncthreads();                         // all raw reads done

  // ---------------- phase 1b: MFMA + in-place writes ----------------
#pragma unroll
  for (int t = 0; t < 2; ++t) {
#pragma unroll
    for (int kt = 0; kt < 2; ++kt) {
      f32x4 d = __builtin_amdgcn_mfma_f32_16x16x32_bf16(af[t], bf[kt], zero, 0, 0, 0);
      if (w < 4) {
        int mt_ = w + t * 4;
#pragma unroll
        for (int r = 0; r < 4; ++r)
          sAp[mt_ * 16 + kb * 4 + r][kt * 16 + lcol] = d[r];
      } else {
        int isI = w < 6;
        int mt_ = (isI ? (w - 4) : (w - 6)) * 2 + t;
#pragma unroll
        for (int r = 0; r < 4; ++r) {
          float* T = isI ? &sAi[mt_ * 16 + kb * 4 + r][kt * 16 + lcol]
                         : &sAj[mt_ * 16 + kb * 4 + r][kt * 16 + lcol];
          *T = d[r];
        }
      }
    }
  }
  __syncthreads();

  // ---------------- phase 2: main compute (validated r7/r12) ----------------
  union { uint32_t u[4]; short8 v; } w2f;  // A = w2^T: row=lcol, k=k8..k8+7
#pragma unroll
  for (int r = 0; r < 4; ++r) {
    float lo = w2[(k8 + 2 * r) * 128 + lcol * 8 + h];
    float hi = w2[(k8 + 2 * r + 1) * 128 + lcol * 8 + h];
    w2f.u[r] = cvt_pk_bf16(lo, hi);
  }
  float w3v[4];
#pragma unroll
  for (int r = 0; r < 4; ++r) w3v[r] = w3[(kb * 4 + r) * 8 + h];

  f32x4 ajA[4], ajB[4];
#pragma unroll
  for (int ng = 0; ng < 4; ++ng) {
    int nl = ng * 16 + lcol;
    ajA[ng] = *(const f32x4*)&sAj[nl][k8];
    ajB[ng] = *(const f32x4*)&sAj[nl][k8 + 4];
  }

  const float* attn_b = attn + (b * NH + h) * SEQ * SEQ;
  float* out_b = out + (b * NH + h) * SEQ * SEQ;
  int bit4 = kb & 1, bit5 = kb & 2;

#pragma unroll
  for (int s = 0; s < 2; ++s) {
    int mb = w * 8 + s * 4;
    float av[4];
    int idxs[4];
#pragma unroll
    for (int ng = 0; ng < 4; ++ng) {
      idxs[ng] = (m0 + mb + kb) * SEQ + n0 + ng * 16 + lcol;
      av[ng] = attn_b[idxs[ng]];
    }
    f32x4 aiA[4], aiB[4];
#pragma unroll
    for (int mi = 0; mi < 4; ++mi) {
      aiA[mi] = *(const f32x4*)&sAi[mb + mi][k8];
      aiB[mi] = *(const f32x4*)&sAi[mb + mi][k8 + 4];
    }
#pragma unroll
    for (int ng = 0; ng < 4; ++ng) {
      int nl = ng * 16 + lcol;
      f32x4 pA[4], pB[4];
#pragma unroll
      for (int mi = 0; mi < 4; ++mi) {
        int rl = mb + mi - nl + 63;
        pA[mi] = *(const f32x4*)&sAp[rl][k8];
        pB[mi] = *(const f32x4*)&sAp[rl][k8 + 4];
      }
      __builtin_amdgcn_sched_barrier(0);
      float part[4];
#pragma unroll
      for (int mi = 0; mi < 4; ++mi) {
        f32x4 s0 = pA[mi] + aiA[mi] + ajA[ng];
        f32x4 s1 = pB[mi] + aiB[mi] + ajB[ng];
        union { uint32_t u[4]; short8 v; } ef;
        ef.u[0] = cvt_pk_bf16(fmaxf(s0[0], 0.f), fmaxf(s0[1], 0.f));
        ef.u[1] = cvt_pk_bf16(fmaxf(s0[2], 0.f), fmaxf(s0[3], 0.f));
        ef.u[2] = cvt_pk_bf16(fmaxf(s1[0], 0.f), fmaxf(s1[1], 0.f));
        ef.u[3] = cvt_pk_bf16(fmaxf(s1[2], 0.f), fmaxf(s1[3], 0.f));
        f32x4 d = __builtin_amdgcn_mfma_f32_16x16x32_bf16(w2f.v, ef.v, zero, 0, 0, 0);
        part[mi] = fmaxf(d[0], 0.f) * w3v[0] + fmaxf(d[1], 0.f) * w3v[1] +
                   fmaxf(d[2], 0.f) * w3v[2] + fmaxf(d[3], 0.f) * w3v[3];
      }
      float mineA = bit4 ? part[1] : part[0];
      float sendA = bit4 ? part[0] : part[1];
      float mineB = bit4 ? part[3] : part[2];
      float sendB = bit4 ? part[2] : part[3];
      mineA += __shfl_xor(sendA, 16, 64);
      mineB += __shfl_xor(sendB, 16, 64);
      float keep = bit5 ? mineB : mineA;
      float send = bit5 ? mineA : mineB;
      float res = keep + __shfl_xor(send, 32, 64);
      out_b[idxs[ng]] = av[ng] + res;
    }
  }
}

extern "C" void kernel_launch(void* const* d_in, const int* in_sizes, int n_in,
                              void* d_out, int out_size, void* d_ws, size_t ws_size,
                              hipStream_t stream) {
  const float* attn = (const float*)d_in[0];
  const int* bseq   = (const int*)d_in[1];
  const int* cseq   = (const int*)d_in[2];
  const float* epos = (const float*)d_in[3];
  const float* ebi  = (const float*)d_in[4];
  const float* ebj  = (const float*)d_in[5];
  const float* eci  = (const float*)d_in[6];
  const float* ecj  = (const float*)d_in[7];
  const float* w1   = (const float*)d_in[8];
  const float* w2   = (const float*)d_in[9];
  const float* w3   = (const float*)d_in[10];
  float* out = (float*)d_out;

  hipLaunchKernelGGL(dis_att_fused, dim3(512), dim3(512), 0, stream,
                     attn, bseq, cseq, epos, ebi, ebj, eci, ecj, w1, w2, w3, out);
}